// Round 5
// baseline (350.756 us; speedup 1.0000x reference)
//
#include <hip/hip_runtime.h>
#include <hip/hip_bf16.h>

// out[n] = sum_k U[k] * relu( x1[n,:] . M[k,:] + c[k] )
//   M[k,d] = V[k,d] + sum_e W[k,d,e]*x2[e]        (K=16, D=128)
//   c[k]   = sum_e V[k,128+e]*x2[e] + b[k]
//
// Main kernel: C(16rows x 16k) tiles via mfma_f32_16x16x32_bf16.
// Precision: x -> bf16 (RNE), M -> bf16 split (Mh + Ml); dot = x*Mh + x*Ml.
// M fragments register-resident; no LDS; x1 streamed with 1-tile register
// prefetch. R4 lesson: __launch_bounds__(256,4) (128-VGPR cap) forced scratch
// spills of the prefetch buffers -> ~100us. This version uncaps (256 VGPR max)
// and shrinks the live set with packed f32->bf16 conversion.

#define D 128
#define KK 16

typedef __attribute__((ext_vector_type(8))) short bf16x8;
typedef __attribute__((ext_vector_type(4))) float f32x4;

__device__ __forceinline__ unsigned short f2bf(float f) {   // RNE
    unsigned u = __float_as_uint(f);
    unsigned t = u + 0x7fffu + ((u >> 16) & 1u);
    return (unsigned short)(t >> 16);
}
__device__ __forceinline__ float bf2f(unsigned short s) {
    return __uint_as_float(((unsigned)s) << 16);
}

// ---------- prep: wave per M element (2048) + wave per c element (16) ----------
// Writes Mh/Ml in B-fragment order: b[kb*512 + lane*8 + j] = bf16(M[n][kb*32+kk])
// where lane = n | ((kk>>3)<<4), j = kk&7  (B[k][n]: n=lane&15, k=(lane>>4)*8+j).
__global__ __launch_bounds__(256) void ntn_prep(const float* __restrict__ x2,
                                                const float* __restrict__ V,
                                                const float* __restrict__ W,
                                                const float* __restrict__ b,
                                                unsigned short* __restrict__ bh,
                                                unsigned short* __restrict__ bl,
                                                float* __restrict__ c) {
    const int gtid = blockIdx.x * 256 + threadIdx.x;
    const int wave = gtid >> 6;
    const int lane = gtid & 63;
    if (wave >= KK * D + KK) return;

    float p;
    if (wave < KK * D) {
        const int k = wave >> 7, d = wave & (D - 1);
        const float* Wr = W + ((size_t)(k * D + d)) * D;
        p = Wr[lane] * x2[lane] + Wr[lane + 64] * x2[lane + 64];
    } else {
        const int k = wave - KK * D;
        const float* Vr = V + (size_t)k * 2 * D + D;
        p = Vr[lane] * x2[lane] + Vr[lane + 64] * x2[lane + 64];
    }
#pragma unroll
    for (int m = 32; m; m >>= 1) p += __shfl_xor(p, m);

    if (lane == 0) {
        if (wave < KK * D) {
            const int k = wave >> 7, d = wave & (D - 1);
            float Mv = V[(size_t)k * 2 * D + d] + p;
            unsigned short hb = f2bf(Mv);
            unsigned short lb = f2bf(Mv - bf2f(hb));
            const int kb = d >> 5, kk = d & 31;
            const int fl = k | ((kk >> 3) << 4);
            const int idx = kb * 512 + fl * 8 + (kk & 7);
            bh[idx] = hb;
            bl[idx] = lb;
        } else {
            const int k = wave - KK * D;
            c[k] = p + b[k];
        }
    }
}

// packed f32x2 -> bf16x2 conversion, 4 pairs -> one bf16x8 A-fragment
__device__ __forceinline__ bf16x8 pack_bf16x8(const float4& a, const float4& b) {
    union { __hip_bfloat162 h2[4]; bf16x8 v; } u;
    u.h2[0] = __float22bfloat162_rn(make_float2(a.x, a.y));
    u.h2[1] = __float22bfloat162_rn(make_float2(a.z, a.w));
    u.h2[2] = __float22bfloat162_rn(make_float2(b.x, b.y));
    u.h2[3] = __float22bfloat162_rn(make_float2(b.z, b.w));
    return u.v;
}

// ---------- main: one wave -> 16-row tiles; M frags register-resident ----------
__global__ __launch_bounds__(256) void ntn_main(const float* __restrict__ x1,
                                                const unsigned short* __restrict__ bhp,
                                                const unsigned short* __restrict__ blp,
                                                const float* __restrict__ cp,
                                                const float* __restrict__ Up,
                                                float* __restrict__ out,
                                                int NT, int TW) {
    const int t = threadIdx.x;
    const int l = t & 63;
    const int gw = blockIdx.x * 4 + (t >> 6);

    // B fragments (loaded once, reused for every tile): 32 VGPR total
    bf16x8 Bh[4], Bl[4];
#pragma unroll
    for (int kb = 0; kb < 4; ++kb) {
        Bh[kb] = *(const bf16x8*)(bhp + kb * 512 + l * 8);
        Bl[kb] = *(const bf16x8*)(blp + kb * 512 + l * 8);
    }
    const int m = l & 15;     // A row within tile / C col (k) owner
    const int q = l >> 4;     // k-quad: A k-range q*8..q*8+7 ; C rows q*4..q*4+3
    const float cl = cp[m];
    const float ul = Up[m];

    int i = gw;
    if (i >= NT) return;

    float4 cur[8];
    {
        const float4* p = (const float4*)(x1 + ((size_t)i * 16 + m) * D + q * 8);
#pragma unroll
        for (int kb = 0; kb < 4; ++kb) { cur[2 * kb] = p[kb * 8]; cur[2 * kb + 1] = p[kb * 8 + 1]; }
    }

    while (true) {
        const int nx = i + TW;
        const bool has = nx < NT;
        float4 nb[8];
        if (has) {
            const float4* p = (const float4*)(x1 + ((size_t)nx * 16 + m) * D + q * 8);
#pragma unroll
            for (int kb = 0; kb < 4; ++kb) { nb[2 * kb] = p[kb * 8]; nb[2 * kb + 1] = p[kb * 8 + 1]; }
        }

        f32x4 accA = {0.f, 0.f, 0.f, 0.f};
        f32x4 accB = {0.f, 0.f, 0.f, 0.f};
#pragma unroll
        for (int kb = 0; kb < 4; ++kb) {
            bf16x8 ah = pack_bf16x8(cur[2 * kb], cur[2 * kb + 1]);
            accA = __builtin_amdgcn_mfma_f32_16x16x32_bf16(ah, Bh[kb], accA, 0, 0, 0);
            accB = __builtin_amdgcn_mfma_f32_16x16x32_bf16(ah, Bl[kb], accB, 0, 0, 0);
        }

        // epilogue: relu + U, reduce over k (16 lanes sharing q), float4 store
        float4 v;
        {
            float vv[4];
#pragma unroll
            for (int r = 0; r < 4; ++r) {
                float s = accA[r] + accB[r] + cl;
                vv[r] = ul * fmaxf(s, 0.f);
                vv[r] += __shfl_xor(vv[r], 1);
                vv[r] += __shfl_xor(vv[r], 2);
                vv[r] += __shfl_xor(vv[r], 4);
                vv[r] += __shfl_xor(vv[r], 8);
            }
            v = make_float4(vv[0], vv[1], vv[2], vv[3]);
        }
        if (m == 0) *(float4*)(out + (size_t)i * 16 + q * 4) = v;

        if (!has) break;
#pragma unroll
        for (int j = 0; j < 8; ++j) cur[j] = nb[j];
        i = nx;
    }
}

extern "C" void kernel_launch(void* const* d_in, const int* in_sizes, int n_in,
                              void* d_out, int out_size, void* d_ws, size_t ws_size,
                              hipStream_t stream) {
    const float* x1 = (const float*)d_in[0];
    const float* x2 = (const float*)d_in[1];
    const float* V  = (const float*)d_in[2];
    const float* W  = (const float*)d_in[3];
    const float* b  = (const float*)d_in[4];
    const float* U  = (const float*)d_in[5];
    float* out = (float*)d_out;

    unsigned short* bh = (unsigned short*)d_ws;          // 2048 bf16
    unsigned short* bl = bh + KK * D;                    // 2048 bf16
    float* c = (float*)(bl + KK * D);                    // 16 f32

    const int N = in_sizes[0] / D;    // 500000
    const int NT = N >> 4;            // 31250 tiles of 16 rows (exact)

    ntn_prep<<<516, 256, 0, stream>>>(x2, V, W, b, bh, bl, c);

    const int blocks = 1024;
    ntn_main<<<blocks, 256, 0, stream>>>(x1, bh, bl, c, U, out, NT, blocks * 4);
}